// Round 6
// baseline (365.774 us; speedup 1.0000x reference)
//
#include <hip/hip_runtime.h>

// SlidingWindowAttention: B=2, L=2048, D=1024, H=16, hd=64, W=256.
// I/O f32; internal bf16 MFMA with f32 accum.
//
// DIAGNOSTIC ROUND (resubmit; round-5 was an infra failure): each kernel
// takes a runtime `reps` arg and repeats its core loop (idempotent;
// accumulators re-zeroed per rep). This inflates each dispatch past the
// 44us harness fills with distinct ranks so rocprof top-5 returns
// per-kernel PMC rows. True dur = dispatch_dur / reps.
#define DIM 1024
#define NH  16
#define HD  64
#define BB  2
#define LL  2048
#define WIN 256
#define MM  (BB * LL)     // 4096 rows
#define NQKV (3 * DIM)    // 3072 fused QKV output cols
#define SEG  (DIM * DIM)

typedef __bf16 bf16x8 __attribute__((ext_vector_type(8)));
typedef float  f32x4  __attribute__((ext_vector_type(4)));
typedef unsigned short u16x8 __attribute__((ext_vector_type(8)));

__device__ __forceinline__ unsigned short f2bf(float f) {
    union { float f; unsigned int i; } v; v.f = f;
    unsigned int r = v.i + 0x7fffu + ((v.i >> 16) & 1u);  // RNE
    return (unsigned short)(r >> 16);
}
__device__ __forceinline__ bf16x8 load8bf(const unsigned short* p) {
    uint4 u = *reinterpret_cast<const uint4*>(p);
    return __builtin_bit_cast(bf16x8, u);
}
__device__ __forceinline__ void gll16(const void* g, void* l) {
    __builtin_amdgcn_global_load_lds(
        (const __attribute__((address_space(1))) unsigned int*)g,
        (__attribute__((address_space(3))) unsigned int*)l, 16, 0, 0);
}

// ---------------------------------------------------------------------------
// Kernel 0: f32 -> bf16 conversion/packing.  reps via laundered offset so
// LICM/DSE cannot collapse the rep loop.
// ---------------------------------------------------------------------------
__global__ __launch_bounds__(256) void convert_inputs(
    const float* __restrict__ x,
    const float* __restrict__ Wq, const float* __restrict__ Wk,
    const float* __restrict__ Wv, const float* __restrict__ Wo,
    unsigned short* __restrict__ xb,
    unsigned short* __restrict__ wqkv,
    unsigned short* __restrict__ wob,
    int reps)
{
    const int y = blockIdx.y;
    const size_t base = ((size_t)blockIdx.x * 256 + threadIdx.x) * 8;
    const float* src; unsigned short* dst;
    if (y < 4)       { src = x + (size_t)y * SEG;  dst = xb + (size_t)y * SEG; }
    else if (y == 4) { src = Wq; dst = wqkv; }
    else if (y == 5) { src = Wk; dst = wqkv + SEG; }
    else if (y == 6) { src = Wv; dst = wqkv + 2 * (size_t)SEG; }
    else             { src = Wo; dst = wob; }
    int z = 0;                               // stays 0; laundered each rep
    #pragma unroll 1
    for (int r = 0; r < reps; ++r) {
        asm volatile("" : "+v"(z));          // opaque to LICM/CSE/DSE
        const float* s2 = src + z;
        unsigned short* d2 = dst + z;
        float4 a = ((const float4*)(s2 + base))[0];
        float4 b = ((const float4*)(s2 + base))[1];
        u16x8 rr;
        rr[0] = f2bf(a.x); rr[1] = f2bf(a.y); rr[2] = f2bf(a.z); rr[3] = f2bf(a.w);
        rr[4] = f2bf(b.x); rr[5] = f2bf(b.y); rr[6] = f2bf(b.z); rr[7] = f2bf(b.w);
        *(u16x8*)(d2 + base) = rr;
    }
}

// ---------------------------------------------------------------------------
// Kernel 1: fused QKV GEMM + RoPE. 128x128 tile, 4 waves (2x2), BK=64.
// reps wraps {acc=0; K-loop}; epilogue once (final rep's acc identical).
// ---------------------------------------------------------------------------
__global__ __launch_bounds__(256, 4) void qkv_gemm(
    const unsigned short* __restrict__ xb,
    const unsigned short* __restrict__ wqkv,
    const float* __restrict__ cosb, const float* __restrict__ sinb,
    unsigned short* __restrict__ qws, unsigned short* __restrict__ kws,
    unsigned short* __restrict__ vT,
    int reps)
{
    __shared__ __align__(16) unsigned short smem[2 * 128 * 64];  // As|Bs 32 KB
    unsigned short* As = smem;
    unsigned short* Bs = smem + 128 * 64;
    const int t = threadIdx.x;
    const int lane = t & 63, w = t >> 6;
    const int wm = w >> 1, wn = w & 1;
    const int lr = lane & 15, quad = lane >> 4;

    const int id   = blockIdx.y * 24 + blockIdx.x;   // 0..767
    const int xcd  = id & 7, slot = id >> 3;         // 96 slots per XCD
    const int bxn  = (xcd & 1) * 12 + (slot % 12);
    const int byn  = (xcd >> 1) * 8 + (slot / 12);
    const int n0 = bxn * 128, m0 = byn * 128;

    f32x4 acc[4][4];

    const int rsub = t >> 3;                 // 0..31
    const int csw  = (t & 7) ^ (rsub & 7);   // swizzled source chunk
    const int sw7  = lr & 7;                 // frag-read swizzle key

    #pragma unroll 1
    for (int r = 0; r < reps; ++r) {
        for (int i = 0; i < 4; i++) for (int j = 0; j < 4; j++) acc[i][j] = 0.0f;
        for (int k0 = 0; k0 < DIM; k0 += 64) {
            __syncthreads();
            #pragma unroll
            for (int p = 0; p < 4; p++) {
                const int row = p * 32 + rsub;
                gll16(xb   + (size_t)(m0 + row) * DIM + k0 + csw * 8,
                      &As[p * 2048 + t * 8]);
                gll16(wqkv + (size_t)(n0 + row) * DIM + k0 + csw * 8,
                      &Bs[p * 2048 + t * 8]);
            }
            __syncthreads();
            #pragma unroll
            for (int kk = 0; kk < 2; kk++) {
                bf16x8 af[4], bfr[4];
                #pragma unroll
                for (int mi = 0; mi < 4; mi++) {
                    const int R = wm * 64 + mi * 16 + lr;
                    af[mi] = load8bf(&As[R * 64 + (((kk * 4 + quad) ^ sw7) * 8)]);
                }
                #pragma unroll
                for (int ni = 0; ni < 4; ni++) {
                    const int R = wn * 64 + ni * 16 + lr;
                    bfr[ni] = load8bf(&Bs[R * 64 + (((kk * 4 + quad) ^ sw7) * 8)]);
                }
                #pragma unroll
                for (int mi = 0; mi < 4; mi++)
                    #pragma unroll
                    for (int ni = 0; ni < 4; ni++)
                        acc[mi][ni] = __builtin_amdgcn_mfma_f32_16x16x32_bf16(
                            af[mi], bfr[ni], acc[mi][ni], 0, 0, 0);
            }
        }
    }

    const int ng = n0 + wn * 64;
    const int which = ng >> 10;            // 0=q 1=k 2=v (wave-uniform)
    const int h = (ng & (DIM - 1)) >> 6;

    if (which == 2) {
        __syncthreads();
        unsigned short* T = smem + w * 2048;
        const int token0 = m0 + wm * 64;
        const int b  = token0 >> 11;
        const int lg = (token0 & (LL - 1)) + (lane & 7) * 8;
        #pragma unroll
        for (int p = 0; p < 2; p++) {
            #pragma unroll
            for (int ni = 2 * p; ni < 2 * p + 2; ni++) {
                const int dl = (ni & 1) * 16 + lr;
                const int g4 = (dl & 7) << 2;
                #pragma unroll
                for (int mi = 0; mi < 4; mi++)
                    #pragma unroll
                    for (int reg = 0; reg < 4; reg++) {
                        const int l = mi * 16 + quad * 4 + reg;
                        const int cw = (l >> 1) ^ g4;
                        T[dl * 64 + cw * 2 + (l & 1)] = f2bf(acc[mi][ni][reg]);
                    }
            }
            #pragma unroll
            for (int s = 0; s < 4; s++) {
                const int dl = s * 8 + (lane >> 3);
                const int d  = p * 32 + dl;
                const int g4 = (dl & 7) << 2;
                const int pd = ((lane & 7) * 4) ^ g4;
                uint4 val = *(const uint4*)&T[dl * 64 + pd * 2];
                *(uint4*)&vT[((size_t)(b * NH + h) * HD + d) * LL + lg] = val;
            }
        }
    } else {
        unsigned short* dst = (which == 0) ? qws : kws;
        #pragma unroll
        for (int mi = 0; mi < 4; mi++) {
            #pragma unroll
            for (int reg = 0; reg < 4; reg++) {
                const int row = m0 + wm * 64 + mi * 16 + quad * 4 + reg;
                const int b = row >> 11, l = row & (LL - 1);
                #pragma unroll
                for (int ni = 0; ni < 4; ni++) {
                    const int d = ni * 16 + lr;
                    const float c = cosb[l * HD + d];
                    const float s = sinb[l * HD + d];
                    const float partner = (d < 32) ? -acc[mi][ni + 2][reg]
                                                   :  acc[mi][ni - 2][reg];
                    dst[((size_t)(b * NH + h) * LL + l) * HD + d] =
                        f2bf(acc[mi][ni][reg] * c + partner * s);
                }
            }
        }
    }
}

// ---------------------------------------------------------------------------
// Kernel 2: sliding-window attention (round-4 verified structure).
// reps wraps {rowsum=0, o=0, full kc loop}; K staging + Q frags once.
// ---------------------------------------------------------------------------
#define SW_SPAN 384
#define PSTR 40   // u16 row stride of chunk-P buffer (16B-aligned rows)
__global__ __launch_bounds__(512, 4) void swa_attn(
    const unsigned short* __restrict__ qws,
    const unsigned short* __restrict__ kws,
    const unsigned short* __restrict__ vT,
    unsigned short* __restrict__ aout,
    int reps)
{
    __shared__ __align__(16) unsigned short Ks[SW_SPAN * 64];     // 48 KB
    __shared__ __align__(16) unsigned short Pc[8][2][16][PSTR];   // 20 KB

    const int t = threadIdx.x;
    const int lane = t & 63, w = t >> 6;          // w = 0..7

    const int id   = (blockIdx.z * NH + blockIdx.y) * 16 + blockIdx.x; // 0..511
    const int xcd  = id & 7, slot = id >> 3;      // slot 0..63
    const int hb   = xcd * 4 + (slot >> 4);       // 0..31
    const int qb   = slot & 15;
    const int h = hb & 15, b = hb >> 4;

    const int q0 = qb * 128;                      // block's 128-query tile
    const int base_key = q0 - WIN;

    const int lr = lane & 15, quad = lane >> 4, ko = quad * 8;
    const size_t base = ((size_t)(b * NH + h)) * LL * HD;
    const unsigned short* Q  = qws + base;
    const unsigned short* K  = kws + base;
    const unsigned short* VT = vT + base;         // [64][LL]

    {   // stage 384 K rows: 6 passes x 64 rows (512 thr x 16B = 8KB/pass)
        const int rsub = t >> 3;                  // 0..63
        const int csw  = (t & 7) ^ (rsub & 7);
        #pragma unroll
        for (int p = 0; p < 6; p++) {
            const int j = min(max(base_key + p * 64 + rsub, 0), LL - 1);
            gll16(K + (size_t)j * HD + csw * 8, &Ks[p * 4096 + t * 8]);
        }
    }
    const int i0 = q0 + w * 16;               // wave's query tile
    const int wkey = i0 - WIN;                // wave's key-span start
    const bf16x8 qa0 = load8bf(Q + (size_t)(i0 + lr) * HD + ko);
    const bf16x8 qa1 = load8bf(Q + (size_t)(i0 + lr) * HD + 32 + ko);
    __syncthreads();                          // the only barrier

    float rowsum[4];
    f32x4 o[4];

    #pragma unroll 1
    for (int r = 0; r < reps; ++r) {
    #pragma unroll
    for (int reg = 0; reg < 4; reg++) rowsum[reg] = 0.f;
    #pragma unroll
    for (int nt = 0; nt < 4; nt++) o[nt] = 0.0f;

    if (q0 >= WIN) {
        // ================= fast path: wkey >= 0 =================
        bool mlo[4], mhi[4];
        #pragma unroll
        for (int reg = 0; reg < 4; reg++) {
            mlo[reg] = (lr >= quad * 4 + reg);   // kt=0 validity
            mhi[reg] = (lr <= quad * 4 + reg);   // kt=16 validity
        }
        #pragma unroll
        for (int kc = 0; kc < 9; kc++) {
            const int pb = kc & 1;               // Pc parity buffer
            // ---- sub 0: kt = 2*kc (even; edge masks at kt==0 and kt==16) ----
            {
                const int kt = 2 * kc;
                const int R = w * 16 + kt * 16 + lr;
                const bf16x8 kb0 = load8bf(&Ks[R * 64 + ((quad       ^ (R & 7)) * 8)]);
                const bf16x8 kb1 = load8bf(&Ks[R * 64 + (((quad + 4) ^ (R & 7)) * 8)]);
                f32x4 s = 0.0f;
                s = __builtin_amdgcn_mfma_f32_16x16x32_bf16(qa0, kb0, s, 0, 0, 0);
                s = __builtin_amdgcn_mfma_f32_16x16x32_bf16(qa1, kb1, s, 0, 0, 0);
                #pragma unroll
                for (int reg = 0; reg < 4; reg++) {
                    float e = __expf(s[reg] * 0.125f);
                    if (kt == 0)  e = mlo[reg] ? e : 0.0f;
                    if (kt == 16) e = mhi[reg] ? e : 0.0f;
                    rowsum[reg] += e;
                    Pc[w][pb][quad * 4 + reg][lr] = f2bf(e);
                }
            }
            // ---- V loads for this chunk (between the score sub-tiles) ----
            bf16x8 bv[4];
            {
                int kb = wkey + kc * 32 + ko;
                kb = min(kb, LL - 8);            // tail clamp: P==0 there
                #pragma unroll
                for (int nt = 0; nt < 4; nt++)
                    bv[nt] = load8bf(VT + (size_t)(nt * 16 + lr) * LL + kb);
            }
            // ---- sub 1: kt = 2*kc+1 (odd; never edge-masked; 17 = pad) ----
            {
                const int kt = 2 * kc + 1;
                if (kt > 16) {                   // kt=17: all-masked pad tile
                    #pragma unroll
                    for (int reg = 0; reg < 4; reg++)
                        Pc[w][pb][quad * 4 + reg][16 + lr] = 0;
                } else {
                    const int R = w * 16 + kt * 16 + lr;
                    const bf16x8 kb0 = load8bf(&Ks[R * 64 + ((quad       ^ (R & 7)) * 8)]);
                    const bf16x8 kb1 = load8bf(&Ks[R * 64 + (((quad + 4) ^ (R & 7)) * 8)]);
                    f32x4 s = 0.0f;
                    s = __builtin_amdgcn_mfma_f32_16x16x32_bf16(qa0, kb0, s, 0, 0, 0);
                    s = __builtin_amdgcn_mfma_f32_16x16x32_bf16(qa1, kb1, s, 0, 0, 0);
                    #pragma unroll
                    for (int reg = 0; reg < 4; reg++) {
                        const float e = __expf(s[reg] * 0.125f);
                        rowsum[reg] += e;
                        Pc[w][pb][quad * 4 + reg][16 + lr] = f2bf(e);
                    }
                }
            }
            const bf16x8 pa = load8bf(&Pc[w][pb][lr][ko]);
            #pragma unroll
            for (int nt = 0; nt < 4; nt++)
                o[nt] = __builtin_amdgcn_mfma_f32_16x16x32_bf16(pa, bv[nt], o[nt], 0, 0, 0);
        }
    } else {
        // ================= slow path (q0 < WIN): full masks =================
        #pragma unroll
        for (int kc = 0; kc < 9; kc++) {
            const int pb = kc & 1;
            #pragma unroll
            for (int sub = 0; sub < 2; sub++) {
                const int kt = 2 * kc + sub;
                const int R = min(w * 16 + kt * 16 + lr, SW_SPAN - 1);
                const bf16x8 kb0 = load8bf(&Ks[R * 64 + ((quad       ^ (R & 7)) * 8)]);
                const bf16x8 kb1 = load8bf(&Ks[R * 64 + (((quad + 4) ^ (R & 7)) * 8)]);
                f32x4 s = 0.0f;
                s = __builtin_amdgcn_mfma_f32_16x16x32_bf16(qa0, kb0, s, 0, 0, 0);
                s = __builtin_amdgcn_mfma_f32_16x16x32_bf16(qa1, kb1, s, 0, 0, 0);
                #pragma unroll
                for (int reg = 0; reg < 4; reg++) {
                    const int i = i0 + quad * 4 + reg;
                    const int j = wkey + kt * 16 + lr;
                    const bool valid = (j >= 0) && (j <= i) && (j >= i - WIN);
                    const float e = valid ? __expf(s[reg] * 0.125f) : 0.0f;
                    rowsum[reg] += e;
                    Pc[w][pb][quad * 4 + reg][sub * 16 + lr] = f2bf(e);
                }
            }
            const bf16x8 pa = load8bf(&Pc[w][pb][lr][ko]);
            int kb = wkey + kc * 32 + ko;
            kb = min(max(kb, 0), LL - 8);
            bf16x8 bv[4];
            #pragma unroll
            for (int nt = 0; nt < 4; nt++)
                bv[nt] = load8bf(VT + (size_t)(nt * 16 + lr) * LL + kb);
            #pragma unroll
            for (int nt = 0; nt < 4; nt++)
                o[nt] = __builtin_amdgcn_mfma_f32_16x16x32_bf16(pa, bv[nt], o[nt], 0, 0, 0);
        }
    }
    }  // reps

    float inv[4];
    #pragma unroll
    for (int reg = 0; reg < 4; reg++) {       // 16-lane butterfly within quad
        float s = rowsum[reg];
        s += __shfl_xor(s, 1); s += __shfl_xor(s, 2);
        s += __shfl_xor(s, 4); s += __shfl_xor(s, 8);
        inv[reg] = 1.0f / s;
    }

    #pragma unroll
    for (int nt = 0; nt < 4; nt++) {
        #pragma unroll
        for (int reg = 0; reg < 4; reg++) {
            const int i = i0 + quad * 4 + reg;
            const int d = nt * 16 + lr;
            aout[((size_t)(b * LL + i)) * DIM + h * HD + d] =
                f2bf(o[nt][reg] * inv[reg]);
        }
    }
}

// ---------------------------------------------------------------------------
// Kernel 3: output projection. 64x64 tiles -> 1024 blocks (4/CU), BK=64.
// reps wraps {acc=0; K-loop}; epilogue once.
// ---------------------------------------------------------------------------
__global__ __launch_bounds__(256, 4) void out_gemm(
    const unsigned short* __restrict__ A,
    const unsigned short* __restrict__ Wob,
    float* __restrict__ out,
    int reps)
{
    __shared__ __align__(16) unsigned short smem[64 * 64 + 64 * 64];  // 16 KB
    unsigned short* As = smem;
    unsigned short* Bs = smem + 64 * 64;
    const int t = threadIdx.x;
    const int lane = t & 63, w = t >> 6;
    const int wm = w >> 1, wn = w & 1;
    const int lr = lane & 15, quad = lane >> 4;

    const int id   = blockIdx.y * 16 + blockIdx.x;   // 0..1023
    const int xcd  = id & 7, slot = id >> 3;         // 128 slots per XCD
    const int bx   = (xcd & 1) * 8 + (slot & 7);
    const int by   = (xcd >> 1) * 16 + (slot >> 3);
    const int n0 = bx * 64, m0 = by * 64;

    f32x4 acc[2][2];

    const int rsub = t >> 3;
    const int csw  = (t & 7) ^ (rsub & 7);
    const int sw7  = lr & 7;

    #pragma unroll 1
    for (int r = 0; r < reps; ++r) {
        for (int i = 0; i < 2; i++) for (int j = 0; j < 2; j++) acc[i][j] = 0.0f;
        for (int k0 = 0; k0 < DIM; k0 += 64) {
            __syncthreads();
            #pragma unroll
            for (int p = 0; p < 2; p++) {
                const int row = p * 32 + rsub;
                gll16(A   + (size_t)(m0 + row) * DIM + k0 + csw * 8,
                      &As[p * 2048 + t * 8]);
                gll16(Wob + (size_t)(n0 + row) * DIM + k0 + csw * 8,
                      &Bs[p * 2048 + t * 8]);
            }
            __syncthreads();
            #pragma unroll
            for (int kk = 0; kk < 2; kk++) {
                bf16x8 af[2], bfr[2];
                #pragma unroll
                for (int mi = 0; mi < 2; mi++) {
                    const int R = wm * 32 + mi * 16 + lr;
                    af[mi] = load8bf(&As[R * 64 + (((kk * 4 + quad) ^ sw7) * 8)]);
                }
                #pragma unroll
                for (int ni = 0; ni < 2; ni++) {
                    const int R = wn * 32 + ni * 16 + lr;
                    bfr[ni] = load8bf(&Bs[R * 64 + (((kk * 4 + quad) ^ sw7) * 8)]);
                }
                #pragma unroll
                for (int mi = 0; mi < 2; mi++)
                    #pragma unroll
                    for (int ni = 0; ni < 2; ni++)
                        acc[mi][ni] = __builtin_amdgcn_mfma_f32_16x16x32_bf16(
                            af[mi], bfr[ni], acc[mi][ni], 0, 0, 0);
            }
        }
    }

    #pragma unroll
    for (int mi = 0; mi < 2; mi++) {
        #pragma unroll
        for (int reg = 0; reg < 4; reg++) {
            const int row = m0 + wm * 32 + mi * 16 + quad * 4 + reg;
            #pragma unroll
            for (int ni = 0; ni < 2; ni++) {
                const int col = n0 + wn * 32 + ni * 16 + lr;
                out[(size_t)row * DIM + col] = acc[mi][ni][reg];
            }
        }
    }
}

extern "C" void kernel_launch(void* const* d_in, const int* in_sizes, int n_in,
                              void* d_out, int out_size, void* d_ws, size_t ws_size,
                              hipStream_t stream)
{
    const float* x    = (const float*)d_in[0];
    const float* cosb = (const float*)d_in[1];
    const float* sinb = (const float*)d_in[2];
    const float* Wq   = (const float*)d_in[3];
    const float* Wk   = (const float*)d_in[4];
    const float* Wv   = (const float*)d_in[5];
    const float* Wo   = (const float*)d_in[6];
    float* out = (float*)d_out;

    unsigned short* xb   = (unsigned short*)d_ws;
    unsigned short* wqkv = xb + (size_t)MM * DIM;
    unsigned short* wob  = wqkv + (size_t)NQKV * DIM;
    unsigned short* qws  = wob + (size_t)DIM * DIM;
    unsigned short* kws  = qws + (size_t)BB * NH * LL * HD;
    unsigned short* vT   = kws + (size_t)BB * NH * LL * HD;
    unsigned short* aws  = xb;   // alias: xb dead after qkv_gemm

    // reps: convert 8, qkv 2, swa 6, out 4 -> distinct dispatch ranks
    convert_inputs<<<dim3(SEG / (256 * 8), 8), 256, 0, stream>>>(
        x, Wq, Wk, Wv, Wo, xb, wqkv, wob, 8);
    qkv_gemm<<<dim3(NQKV / 128, MM / 128), 256, 0, stream>>>(
        xb, wqkv, cosb, sinb, qws, kws, vT, 2);
    swa_attn<<<dim3(LL / 128, NH, BB), 512, 0, stream>>>(qws, kws, vT, aws, 6);
    out_gemm<<<dim3(DIM / 64, MM / 64), 256, 0, stream>>>(aws, wob, out, 4);
}

// Round 8
// 158.516 us; speedup vs baseline: 2.3075x; 2.3075x over previous
//
#include <hip/hip_runtime.h>

// SlidingWindowAttention: B=2, L=2048, D=1024, H=16, hd=64, W=256.
// I/O f32; internal bf16 MFMA with f32 accum.
#define DIM 1024
#define NH  16
#define HD  64
#define BB  2
#define LL  2048
#define WIN 256
#define MM  (BB * LL)     // 4096 rows
#define NQKV (3 * DIM)    // 3072 fused QKV output cols
#define SEG  (DIM * DIM)

typedef __bf16 bf16x8 __attribute__((ext_vector_type(8)));
typedef float  f32x4  __attribute__((ext_vector_type(4)));
typedef unsigned short u16x8 __attribute__((ext_vector_type(8)));

__device__ __forceinline__ unsigned short f2bf(float f) {
    union { float f; unsigned int i; } v; v.f = f;
    unsigned int r = v.i + 0x7fffu + ((v.i >> 16) & 1u);  // RNE
    return (unsigned short)(r >> 16);
}
__device__ __forceinline__ bf16x8 load8bf(const unsigned short* p) {
    uint4 u = *reinterpret_cast<const uint4*>(p);
    return __builtin_bit_cast(bf16x8, u);
}
__device__ __forceinline__ void gll16(const void* g, void* l) {
    __builtin_amdgcn_global_load_lds(
        (const __attribute__((address_space(1))) unsigned int*)g,
        (__attribute__((address_space(3))) unsigned int*)l, 16, 0, 0);
}
// Pack two f32 -> one dword of 2 bf16 (lo in bits 15:0). Pure C, RNE —
// replaces round-7's v_cvt_pk_bf16_f32 asm (suspected hi/lo packing bug).
__device__ __forceinline__ unsigned pack2bf(float lo, float hi) {
    return (unsigned)f2bf(lo) | ((unsigned)f2bf(hi) << 16);
}

// ---------------------------------------------------------------------------
// Kernel 0: f32 -> bf16 conversion/packing.
// ---------------------------------------------------------------------------
__global__ __launch_bounds__(256) void convert_inputs(
    const float* __restrict__ x,
    const float* __restrict__ Wq, const float* __restrict__ Wk,
    const float* __restrict__ Wv, const float* __restrict__ Wo,
    unsigned short* __restrict__ xb,
    unsigned short* __restrict__ wqkv,
    unsigned short* __restrict__ wob)
{
    const int y = blockIdx.y;
    const size_t base = ((size_t)blockIdx.x * 256 + threadIdx.x) * 8;
    const float* src; unsigned short* dst;
    if (y < 4)       { src = x + (size_t)y * SEG;  dst = xb + (size_t)y * SEG; }
    else if (y == 4) { src = Wq; dst = wqkv; }
    else if (y == 5) { src = Wk; dst = wqkv + SEG; }
    else if (y == 6) { src = Wv; dst = wqkv + 2 * (size_t)SEG; }
    else             { src = Wo; dst = wob; }
    float4 a = ((const float4*)(src + base))[0];
    float4 b = ((const float4*)(src + base))[1];
    u16x8 r;
    r[0] = f2bf(a.x); r[1] = f2bf(a.y); r[2] = f2bf(a.z); r[3] = f2bf(a.w);
    r[4] = f2bf(b.x); r[5] = f2bf(b.y); r[6] = f2bf(b.z); r[7] = f2bf(b.w);
    *(u16x8*)(dst + base) = r;
}

// ---------------------------------------------------------------------------
// Kernel 1: fused QKV GEMM + RoPE. 128x128 tile, 4 waves (2x2), BK=64,
// launch_bounds(256,4), 8-chunk XOR swizzled staging, XCD-aware remap.
// ---------------------------------------------------------------------------
__global__ __launch_bounds__(256, 4) void qkv_gemm(
    const unsigned short* __restrict__ xb,
    const unsigned short* __restrict__ wqkv,
    const float* __restrict__ cosb, const float* __restrict__ sinb,
    unsigned short* __restrict__ qws, unsigned short* __restrict__ kws,
    unsigned short* __restrict__ vT)
{
    __shared__ __align__(16) unsigned short smem[2 * 128 * 64];  // As|Bs 32 KB
    unsigned short* As = smem;
    unsigned short* Bs = smem + 128 * 64;
    const int t = threadIdx.x;
    const int lane = t & 63, w = t >> 6;
    const int wm = w >> 1, wn = w & 1;
    const int lr = lane & 15, quad = lane >> 4;

    const int id   = blockIdx.y * 24 + blockIdx.x;   // 0..767
    const int xcd  = id & 7, slot = id >> 3;         // 96 slots per XCD
    const int bxn  = (xcd & 1) * 12 + (slot % 12);
    const int byn  = (xcd >> 1) * 8 + (slot / 12);
    const int n0 = bxn * 128, m0 = byn * 128;

    f32x4 acc[4][4];
    for (int i = 0; i < 4; i++) for (int j = 0; j < 4; j++) acc[i][j] = 0.0f;

    const int rsub = t >> 3;                 // 0..31
    const int csw  = (t & 7) ^ (rsub & 7);   // swizzled source chunk
    const int sw7  = lr & 7;                 // frag-read swizzle key

    for (int k0 = 0; k0 < DIM; k0 += 64) {
        __syncthreads();
        #pragma unroll
        for (int p = 0; p < 4; p++) {
            const int row = p * 32 + rsub;
            gll16(xb   + (size_t)(m0 + row) * DIM + k0 + csw * 8,
                  &As[p * 2048 + t * 8]);
            gll16(wqkv + (size_t)(n0 + row) * DIM + k0 + csw * 8,
                  &Bs[p * 2048 + t * 8]);
        }
        __syncthreads();
        #pragma unroll
        for (int kk = 0; kk < 2; kk++) {
            bf16x8 af[4], bfr[4];
            #pragma unroll
            for (int mi = 0; mi < 4; mi++) {
                const int R = wm * 64 + mi * 16 + lr;
                af[mi] = load8bf(&As[R * 64 + (((kk * 4 + quad) ^ sw7) * 8)]);
            }
            #pragma unroll
            for (int ni = 0; ni < 4; ni++) {
                const int R = wn * 64 + ni * 16 + lr;
                bfr[ni] = load8bf(&Bs[R * 64 + (((kk * 4 + quad) ^ sw7) * 8)]);
            }
            #pragma unroll
            for (int mi = 0; mi < 4; mi++)
                #pragma unroll
                for (int ni = 0; ni < 4; ni++)
                    acc[mi][ni] = __builtin_amdgcn_mfma_f32_16x16x32_bf16(
                        af[mi], bfr[ni], acc[mi][ni], 0, 0, 0);
        }
    }

    const int ng = n0 + wn * 64;
    const int which = ng >> 10;            // 0=q 1=k 2=v (wave-uniform)
    const int h = (ng & (DIM - 1)) >> 6;

    if (which == 2) {
        __syncthreads();
        unsigned short* T = smem + w * 2048;
        const int token0 = m0 + wm * 64;
        const int b  = token0 >> 11;
        const int lg = (token0 & (LL - 1)) + (lane & 7) * 8;
        #pragma unroll
        for (int p = 0; p < 2; p++) {
            #pragma unroll
            for (int ni = 2 * p; ni < 2 * p + 2; ni++) {
                const int dl = (ni & 1) * 16 + lr;
                const int g4 = (dl & 7) << 2;
                #pragma unroll
                for (int mi = 0; mi < 4; mi++)
                    #pragma unroll
                    for (int reg = 0; reg < 4; reg++) {
                        const int l = mi * 16 + quad * 4 + reg;
                        const int cw = (l >> 1) ^ g4;
                        T[dl * 64 + cw * 2 + (l & 1)] = f2bf(acc[mi][ni][reg]);
                    }
            }
            #pragma unroll
            for (int s = 0; s < 4; s++) {
                const int dl = s * 8 + (lane >> 3);
                const int d  = p * 32 + dl;
                const int g4 = (dl & 7) << 2;
                const int pd = ((lane & 7) * 4) ^ g4;
                uint4 val = *(const uint4*)&T[dl * 64 + pd * 2];
                *(uint4*)&vT[((size_t)(b * NH + h) * HD + d) * LL + lg] = val;
            }
        }
    } else {
        unsigned short* dst = (which == 0) ? qws : kws;
        #pragma unroll
        for (int mi = 0; mi < 4; mi++) {
            #pragma unroll
            for (int reg = 0; reg < 4; reg++) {
                const int row = m0 + wm * 64 + mi * 16 + quad * 4 + reg;
                const int b = row >> 11, l = row & (LL - 1);
                #pragma unroll
                for (int ni = 0; ni < 4; ni++) {
                    const int d = ni * 16 + lr;
                    const float c = cosb[l * HD + d];
                    const float s = sinb[l * HD + d];
                    const float partner = (d < 32) ? -acc[mi][ni + 2][reg]
                                                   :  acc[mi][ni - 2][reg];
                    dst[((size_t)(b * NH + h) * LL + l) * HD + d] =
                        f2bf(acc[mi][ni][reg] * c + partner * s);
                }
            }
        }
    }
}

// ---------------------------------------------------------------------------
// Kernel 2: sliding-window attention — in-register P (swapped QK^T).
// Round-7 failed (absmax 0.186); derivation re-verified against the passing
// round-4 kernel's composite MFMA maps — layout algebra is sound. Suspects
// were the two unverified primitives. This round substitutes both:
//   cvt_pk asm  -> pack2bf (pure-C RNE, deterministic lo/hi order)
//   ds_bpermute -> __shfl (same hw op, known-good semantics)
// Redistribution (unchanged theory): lane holds S[key=quad*4+reg][q=lr];
// target (qT,lr) needs P[q=lr][kk=8qT..8qT+7] from lanes (qT&1)*32+lr and
// +16, words L/H of sub (qT>>1).
// Masks transpose: kt=0 valid iff qk>=lr; kt=16 valid iff qk<=lr.
// LDS 48KB (Ks only). rowsum: butterfly xor 16,32 over quads.
// ---------------------------------------------------------------------------
#define SW_SPAN 384
__global__ __launch_bounds__(512, 4) void swa_attn(
    const unsigned short* __restrict__ qws,
    const unsigned short* __restrict__ kws,
    const unsigned short* __restrict__ vT,
    unsigned short* __restrict__ aout)
{
    __shared__ __align__(16) unsigned short Ks[SW_SPAN * 64];     // 48 KB

    const int t = threadIdx.x;
    const int lane = t & 63, w = t >> 6;          // w = 0..7

    const int id   = (blockIdx.z * NH + blockIdx.y) * 16 + blockIdx.x; // 0..511
    const int xcd  = id & 7, slot = id >> 3;      // slot 0..63
    const int hb   = xcd * 4 + (slot >> 4);       // 0..31
    const int qb   = slot & 15;
    const int h = hb & 15, b = hb >> 4;

    const int q0 = qb * 128;                      // block's 128-query tile
    const int base_key = q0 - WIN;

    const int lr = lane & 15, quad = lane >> 4, ko = quad * 8;
    const size_t base = ((size_t)(b * NH + h)) * LL * HD;
    const unsigned short* Q  = qws + base;
    const unsigned short* K  = kws + base;
    const unsigned short* VT = vT + base;         // [64][LL]

    {   // stage 384 K rows: 6 passes x 64 rows (512 thr x 16B = 8KB/pass)
        const int rsub = t >> 3;                  // 0..63
        const int csw  = (t & 7) ^ (rsub & 7);
        #pragma unroll
        for (int p = 0; p < 6; p++) {
            const int j = min(max(base_key + p * 64 + rsub, 0), LL - 1);
            gll16(K + (size_t)j * HD + csw * 8, &Ks[p * 4096 + t * 8]);
        }
    }
    const int i0 = q0 + w * 16;               // wave's query tile
    const int wkey = i0 - WIN;                // wave's key-span start
    const bf16x8 qa0 = load8bf(Q + (size_t)(i0 + lr) * HD + ko);
    const bf16x8 qa1 = load8bf(Q + (size_t)(i0 + lr) * HD + 32 + ko);
    __syncthreads();                          // the only barrier

    float rowsumL = 0.f;
    f32x4 o[4];
    #pragma unroll
    for (int nt = 0; nt < 4; nt++) o[nt] = 0.0f;

    // shuffle source lanes: group {lr, lr+16, lr+32, lr+48}
    const int srcA = (quad & 1) * 32 + lr;
    const int srcB = srcA + 16;
    const bool useB = (quad >= 2);

    if (q0 >= WIN) {
        // ================= fast path: wkey >= 0 =================
        #pragma unroll
        for (int kc = 0; kc < 9; kc++) {
            // ---- V loads for this kc (consumed after both subs) ----
            bf16x8 bv[4];
            {
                int kb = wkey + kc * 32 + ko;
                kb = min(kb, LL - 8);            // tail clamp: P==0 there
                #pragma unroll
                for (int nt = 0; nt < 4; nt++)
                    bv[nt] = load8bf(VT + (size_t)(nt * 16 + lr) * LL + kb);
            }
            unsigned L0, H0, L1, H1;
            // ---- sub 0: kt = 2*kc (even; masks at kt==0 and kt==16) ----
            {
                const int kt = 2 * kc;
                const int R = w * 16 + kt * 16 + lr;
                const bf16x8 kb0 = load8bf(&Ks[R * 64 + ((quad       ^ (R & 7)) * 8)]);
                const bf16x8 kb1 = load8bf(&Ks[R * 64 + (((quad + 4) ^ (R & 7)) * 8)]);
                f32x4 s = 0.0f;
                __builtin_amdgcn_s_setprio(1);
                s = __builtin_amdgcn_mfma_f32_16x16x32_bf16(kb0, qa0, s, 0, 0, 0);
                s = __builtin_amdgcn_mfma_f32_16x16x32_bf16(kb1, qa1, s, 0, 0, 0);
                __builtin_amdgcn_s_setprio(0);
                float e[4];
                #pragma unroll
                for (int reg = 0; reg < 4; reg++) {
                    const int qk = quad * 4 + reg;       // key index in tile
                    float ee = __expf(s[reg] * 0.125f);
                    if (kt == 0)  ee = (qk >= lr) ? ee : 0.0f;
                    if (kt == 16) ee = (qk <= lr) ? ee : 0.0f;
                    rowsumL += ee;
                    e[reg] = ee;
                }
                L0 = pack2bf(e[0], e[1]); H0 = pack2bf(e[2], e[3]);
            }
            // ---- sub 1: kt = 2*kc+1 (odd; never edge-masked; 17 = pad) ----
            {
                const int kt = 2 * kc + 1;
                if (kt > 16) {
                    L1 = 0u; H1 = 0u;
                } else {
                    const int R = w * 16 + kt * 16 + lr;
                    const bf16x8 kb0 = load8bf(&Ks[R * 64 + ((quad       ^ (R & 7)) * 8)]);
                    const bf16x8 kb1 = load8bf(&Ks[R * 64 + (((quad + 4) ^ (R & 7)) * 8)]);
                    f32x4 s = 0.0f;
                    __builtin_amdgcn_s_setprio(1);
                    s = __builtin_amdgcn_mfma_f32_16x16x32_bf16(kb0, qa0, s, 0, 0, 0);
                    s = __builtin_amdgcn_mfma_f32_16x16x32_bf16(kb1, qa1, s, 0, 0, 0);
                    __builtin_amdgcn_s_setprio(0);
                    float e[4];
                    #pragma unroll
                    for (int reg = 0; reg < 4; reg++) {
                        const float ee = __expf(s[reg] * 0.125f);
                        rowsumL += ee;
                        e[reg] = ee;
                    }
                    L1 = pack2bf(e[0], e[1]); H1 = pack2bf(e[2], e[3]);
                }
            }
            // ---- in-register P redistribution (8 shfl + 4 select) ----
            {
                const int a0 = __shfl((int)L0, srcA);
                const int a1 = __shfl((int)H0, srcA);
                const int a2 = __shfl((int)L0, srcB);
                const int a3 = __shfl((int)H0, srcB);
                const int b0 = __shfl((int)L1, srcA);
                const int b1 = __shfl((int)H1, srcA);
                const int b2 = __shfl((int)L1, srcB);
                const int b3 = __shfl((int)H1, srcB);
                uint4 w4;
                w4.x = (unsigned)(useB ? b0 : a0);
                w4.y = (unsigned)(useB ? b1 : a1);
                w4.z = (unsigned)(useB ? b2 : a2);
                w4.w = (unsigned)(useB ? b3 : a3);
                const bf16x8 pa = __builtin_bit_cast(bf16x8, w4);
                __builtin_amdgcn_s_setprio(1);
                #pragma unroll
                for (int nt = 0; nt < 4; nt++)
                    o[nt] = __builtin_amdgcn_mfma_f32_16x16x32_bf16(pa, bv[nt], o[nt], 0, 0, 0);
                __builtin_amdgcn_s_setprio(0);
            }
        }
    } else {
        // ================= slow path (q0 < WIN): full masks =================
        #pragma unroll
        for (int kc = 0; kc < 9; kc++) {
            bf16x8 bv[4];
            {
                int kb = wkey + kc * 32 + ko;
                kb = min(max(kb, 0), LL - 8);
                #pragma unroll
                for (int nt = 0; nt < 4; nt++)
                    bv[nt] = load8bf(VT + (size_t)(nt * 16 + lr) * LL + kb);
            }
            unsigned LH[2][2];
            #pragma unroll
            for (int sub = 0; sub < 2; sub++) {
                const int kt = 2 * kc + sub;
                const int R = min(w * 16 + kt * 16 + lr, SW_SPAN - 1);
                const bf16x8 kb0 = load8bf(&Ks[R * 64 + ((quad       ^ (R & 7)) * 8)]);
                const bf16x8 kb1 = load8bf(&Ks[R * 64 + (((quad + 4) ^ (R & 7)) * 8)]);
                f32x4 s = 0.0f;
                s = __builtin_amdgcn_mfma_f32_16x16x32_bf16(kb0, qa0, s, 0, 0, 0);
                s = __builtin_amdgcn_mfma_f32_16x16x32_bf16(kb1, qa1, s, 0, 0, 0);
                float e[4];
                #pragma unroll
                for (int reg = 0; reg < 4; reg++) {
                    const int qk = quad * 4 + reg;
                    const int i = i0 + lr;                    // query row
                    const int j = wkey + kt * 16 + qk;        // key index
                    const bool valid = (j >= 0) && (j <= i) && (j >= i - WIN);
                    const float ee = valid ? __expf(s[reg] * 0.125f) : 0.0f;
                    rowsumL += ee;
                    e[reg] = ee;
                }
                LH[sub][0] = pack2bf(e[0], e[1]); LH[sub][1] = pack2bf(e[2], e[3]);
            }
            {
                const int a0 = __shfl((int)LH[0][0], srcA);
                const int a1 = __shfl((int)LH[0][1], srcA);
                const int a2 = __shfl((int)LH[0][0], srcB);
                const int a3 = __shfl((int)LH[0][1], srcB);
                const int b0 = __shfl((int)LH[1][0], srcA);
                const int b1 = __shfl((int)LH[1][1], srcA);
                const int b2 = __shfl((int)LH[1][0], srcB);
                const int b3 = __shfl((int)LH[1][1], srcB);
                uint4 w4;
                w4.x = (unsigned)(useB ? b0 : a0);
                w4.y = (unsigned)(useB ? b1 : a1);
                w4.z = (unsigned)(useB ? b2 : a2);
                w4.w = (unsigned)(useB ? b3 : a3);
                const bf16x8 pa = __builtin_bit_cast(bf16x8, w4);
                #pragma unroll
                for (int nt = 0; nt < 4; nt++)
                    o[nt] = __builtin_amdgcn_mfma_f32_16x16x32_bf16(pa, bv[nt], o[nt], 0, 0, 0);
            }
        }
    }

    // rowsum: butterfly over the 4 quads -> every lane has full sum for q=lr
    rowsumL += __shfl_xor(rowsumL, 16);
    rowsumL += __shfl_xor(rowsumL, 32);
    const float inv = 1.0f / rowsumL;

    // o[nt][reg] is for q-row quad*4+reg -> fetch that row's inv (lane<16 has q=lane)
    float invq[4];
    #pragma unroll
    for (int reg = 0; reg < 4; reg++)
        invq[reg] = __shfl(inv, quad * 4 + reg);

    #pragma unroll
    for (int nt = 0; nt < 4; nt++) {
        #pragma unroll
        for (int reg = 0; reg < 4; reg++) {
            const int i = i0 + quad * 4 + reg;
            const int d = nt * 16 + lr;
            aout[((size_t)(b * LL + i)) * DIM + h * HD + d] =
                f2bf(o[nt][reg] * invq[reg]);
        }
    }
}

// ---------------------------------------------------------------------------
// Kernel 3: output projection. 64x64 tiles -> 1024 blocks (4/CU), BK=64,
// swizzled staging, XCD-aware remap. Wave = 32M x 32N.
// ---------------------------------------------------------------------------
__global__ __launch_bounds__(256, 4) void out_gemm(
    const unsigned short* __restrict__ A,
    const unsigned short* __restrict__ Wob,
    float* __restrict__ out)
{
    __shared__ __align__(16) unsigned short smem[64 * 64 + 64 * 64];  // 16 KB
    unsigned short* As = smem;
    unsigned short* Bs = smem + 64 * 64;
    const int t = threadIdx.x;
    const int lane = t & 63, w = t >> 6;
    const int wm = w >> 1, wn = w & 1;
    const int lr = lane & 15, quad = lane >> 4;

    const int id   = blockIdx.y * 16 + blockIdx.x;   // 0..1023
    const int xcd  = id & 7, slot = id >> 3;         // 128 slots per XCD
    const int bx   = (xcd & 1) * 8 + (slot & 7);
    const int by   = (xcd >> 1) * 16 + (slot >> 3);
    const int n0 = bx * 64, m0 = by * 64;

    f32x4 acc[2][2];
    for (int i = 0; i < 2; i++) for (int j = 0; j < 2; j++) acc[i][j] = 0.0f;

    const int rsub = t >> 3;
    const int csw  = (t & 7) ^ (rsub & 7);
    const int sw7  = lr & 7;

    for (int k0 = 0; k0 < DIM; k0 += 64) {
        __syncthreads();
        #pragma unroll
        for (int p = 0; p < 2; p++) {
            const int row = p * 32 + rsub;
            gll16(A   + (size_t)(m0 + row) * DIM + k0 + csw * 8,
                  &As[p * 2048 + t * 8]);
            gll16(Wob + (size_t)(n0 + row) * DIM + k0 + csw * 8,
                  &Bs[p * 2048 + t * 8]);
        }
        __syncthreads();
        #pragma unroll
        for (int kk = 0; kk < 2; kk++) {
            bf16x8 af[2], bfr[2];
            #pragma unroll
            for (int mi = 0; mi < 2; mi++) {
                const int R = wm * 32 + mi * 16 + lr;
                af[mi] = load8bf(&As[R * 64 + (((kk * 4 + quad) ^ sw7) * 8)]);
            }
            #pragma unroll
            for (int ni = 0; ni < 2; ni++) {
                const int R = wn * 32 + ni * 16 + lr;
                bfr[ni] = load8bf(&Bs[R * 64 + (((kk * 4 + quad) ^ sw7) * 8)]);
            }
            #pragma unroll
            for (int mi = 0; mi < 2; mi++)
                #pragma unroll
                for (int ni = 0; ni < 2; ni++)
                    acc[mi][ni] = __builtin_amdgcn_mfma_f32_16x16x32_bf16(
                        af[mi], bfr[ni], acc[mi][ni], 0, 0, 0);
        }
    }

    #pragma unroll
    for (int mi = 0; mi < 2; mi++) {
        #pragma unroll
        for (int reg = 0; reg < 4; reg++) {
            const int row = m0 + wm * 32 + mi * 16 + quad * 4 + reg;
            #pragma unroll
            for (int ni = 0; ni < 2; ni++) {
                const int col = n0 + wn * 32 + ni * 16 + lr;
                out[(size_t)row * DIM + col] = acc[mi][ni][reg];
            }
        }
    }
}

extern "C" void kernel_launch(void* const* d_in, const int* in_sizes, int n_in,
                              void* d_out, int out_size, void* d_ws, size_t ws_size,
                              hipStream_t stream)
{
    const float* x    = (const float*)d_in[0];
    const float* cosb = (const float*)d_in[1];
    const float* sinb = (const float*)d_in[2];
    const float* Wq   = (const float*)d_in[3];
    const float* Wk   = (const float*)d_in[4];
    const float* Wv   = (const float*)d_in[5];
    const float* Wo   = (const float*)d_in[6];
    float* out = (float*)d_out;

    unsigned short* xb   = (unsigned short*)d_ws;
    unsigned short* wqkv = xb + (size_t)MM * DIM;
    unsigned short* wob  = wqkv + (size_t)NQKV * DIM;
    unsigned short* qws  = wob + (size_t)DIM * DIM;
    unsigned short* kws  = qws + (size_t)BB * NH * LL * HD;
    unsigned short* vT   = kws + (size_t)BB * NH * LL * HD;
    unsigned short* aws  = xb;   // alias: xb dead after qkv_gemm

    convert_inputs<<<dim3(SEG / (256 * 8), 8), 256, 0, stream>>>(
        x, Wq, Wk, Wv, Wo, xb, wqkv, wob);
    qkv_gemm<<<dim3(NQKV / 128, MM / 128), 256, 0, stream>>>(
        xb, wqkv, cosb, sinb, qws, kws, vT);
    swa_attn<<<dim3(LL / 128, NH, BB), 512, 0, stream>>>(qws, kws, vT, aws);
    out_gemm<<<dim3(DIM / 64, MM / 64), 256, 0, stream>>>(aws, wob, out);
}

// Round 9
// 152.011 us; speedup vs baseline: 2.4062x; 1.0428x over previous
//
#include <hip/hip_runtime.h>

// SlidingWindowAttention: B=2, L=2048, D=1024, H=16, hd=64, W=256.
// I/O f32; internal bf16 MFMA with f32 accum.
#define DIM 1024
#define NH  16
#define HD  64
#define BB  2
#define LL  2048
#define WIN 256
#define MM  (BB * LL)     // 4096 rows
#define NQKV (3 * DIM)    // 3072 fused QKV output cols
#define SEG  (DIM * DIM)

typedef __bf16 bf16x8 __attribute__((ext_vector_type(8)));
typedef float  f32x4  __attribute__((ext_vector_type(4)));
typedef unsigned short u16x8 __attribute__((ext_vector_type(8)));

__device__ __forceinline__ unsigned short f2bf(float f) {
    union { float f; unsigned int i; } v; v.f = f;
    unsigned int r = v.i + 0x7fffu + ((v.i >> 16) & 1u);  // RNE
    return (unsigned short)(r >> 16);
}
__device__ __forceinline__ bf16x8 load8bf(const unsigned short* p) {
    uint4 u = *reinterpret_cast<const uint4*>(p);
    return __builtin_bit_cast(bf16x8, u);
}
__device__ __forceinline__ void gll16(const void* g, void* l) {
    __builtin_amdgcn_global_load_lds(
        (const __attribute__((address_space(1))) unsigned int*)g,
        (__attribute__((address_space(3))) unsigned int*)l, 16, 0, 0);
}
// Pack two f32 -> one dword of 2 bf16 (lo in bits 15:0). Pure C, RNE.
__device__ __forceinline__ unsigned pack2bf(float lo, float hi) {
    return (unsigned)f2bf(lo) | ((unsigned)f2bf(hi) << 16);
}

// ---------------------------------------------------------------------------
// Kernel 0: f32 -> bf16 conversion/packing.
// ---------------------------------------------------------------------------
__global__ __launch_bounds__(256) void convert_inputs(
    const float* __restrict__ x,
    const float* __restrict__ Wq, const float* __restrict__ Wk,
    const float* __restrict__ Wv, const float* __restrict__ Wo,
    unsigned short* __restrict__ xb,
    unsigned short* __restrict__ wqkv,
    unsigned short* __restrict__ wob)
{
    const int y = blockIdx.y;
    const size_t base = ((size_t)blockIdx.x * 256 + threadIdx.x) * 8;
    const float* src; unsigned short* dst;
    if (y < 4)       { src = x + (size_t)y * SEG;  dst = xb + (size_t)y * SEG; }
    else if (y == 4) { src = Wq; dst = wqkv; }
    else if (y == 5) { src = Wk; dst = wqkv + SEG; }
    else if (y == 6) { src = Wv; dst = wqkv + 2 * (size_t)SEG; }
    else             { src = Wo; dst = wob; }
    float4 a = ((const float4*)(src + base))[0];
    float4 b = ((const float4*)(src + base))[1];
    u16x8 r;
    r[0] = f2bf(a.x); r[1] = f2bf(a.y); r[2] = f2bf(a.z); r[3] = f2bf(a.w);
    r[4] = f2bf(b.x); r[5] = f2bf(b.y); r[6] = f2bf(b.z); r[7] = f2bf(b.w);
    *(u16x8*)(dst + base) = r;
}

// ---------------------------------------------------------------------------
// Kernel 1: fused QKV GEMM + RoPE. 128x128 tile, 4 waves (2x2), BK=64,
// launch_bounds(256,4), 8-chunk XOR swizzled staging, XCD-aware remap.
// ---------------------------------------------------------------------------
__global__ __launch_bounds__(256, 4) void qkv_gemm(
    const unsigned short* __restrict__ xb,
    const unsigned short* __restrict__ wqkv,
    const float* __restrict__ cosb, const float* __restrict__ sinb,
    unsigned short* __restrict__ qws, unsigned short* __restrict__ kws,
    unsigned short* __restrict__ vT)
{
    __shared__ __align__(16) unsigned short smem[2 * 128 * 64];  // As|Bs 32 KB
    unsigned short* As = smem;
    unsigned short* Bs = smem + 128 * 64;
    const int t = threadIdx.x;
    const int lane = t & 63, w = t >> 6;
    const int wm = w >> 1, wn = w & 1;
    const int lr = lane & 15, quad = lane >> 4;

    const int id   = blockIdx.y * 24 + blockIdx.x;   // 0..767
    const int xcd  = id & 7, slot = id >> 3;         // 96 slots per XCD
    const int bxn  = (xcd & 1) * 12 + (slot % 12);
    const int byn  = (xcd >> 1) * 8 + (slot / 12);
    const int n0 = bxn * 128, m0 = byn * 128;

    f32x4 acc[4][4];
    for (int i = 0; i < 4; i++) for (int j = 0; j < 4; j++) acc[i][j] = 0.0f;

    const int rsub = t >> 3;                 // 0..31
    const int csw  = (t & 7) ^ (rsub & 7);   // swizzled source chunk
    const int sw7  = lr & 7;                 // frag-read swizzle key

    for (int k0 = 0; k0 < DIM; k0 += 64) {
        __syncthreads();
        #pragma unroll
        for (int p = 0; p < 4; p++) {
            const int row = p * 32 + rsub;
            gll16(xb   + (size_t)(m0 + row) * DIM + k0 + csw * 8,
                  &As[p * 2048 + t * 8]);
            gll16(wqkv + (size_t)(n0 + row) * DIM + k0 + csw * 8,
                  &Bs[p * 2048 + t * 8]);
        }
        __syncthreads();
        #pragma unroll
        for (int kk = 0; kk < 2; kk++) {
            bf16x8 af[4], bfr[4];
            #pragma unroll
            for (int mi = 0; mi < 4; mi++) {
                const int R = wm * 64 + mi * 16 + lr;
                af[mi] = load8bf(&As[R * 64 + (((kk * 4 + quad) ^ sw7) * 8)]);
            }
            #pragma unroll
            for (int ni = 0; ni < 4; ni++) {
                const int R = wn * 64 + ni * 16 + lr;
                bfr[ni] = load8bf(&Bs[R * 64 + (((kk * 4 + quad) ^ sw7) * 8)]);
            }
            #pragma unroll
            for (int mi = 0; mi < 4; mi++)
                #pragma unroll
                for (int ni = 0; ni < 4; ni++)
                    acc[mi][ni] = __builtin_amdgcn_mfma_f32_16x16x32_bf16(
                        af[mi], bfr[ni], acc[mi][ni], 0, 0, 0);
        }
    }

    const int ng = n0 + wn * 64;
    const int which = ng >> 10;            // 0=q 1=k 2=v (wave-uniform)
    const int h = (ng & (DIM - 1)) >> 6;

    if (which == 2) {
        __syncthreads();
        unsigned short* T = smem + w * 2048;
        const int token0 = m0 + wm * 64;
        const int b  = token0 >> 11;
        const int lg = (token0 & (LL - 1)) + (lane & 7) * 8;
        #pragma unroll
        for (int p = 0; p < 2; p++) {
            #pragma unroll
            for (int ni = 2 * p; ni < 2 * p + 2; ni++) {
                const int dl = (ni & 1) * 16 + lr;
                const int g4 = (dl & 7) << 2;
                #pragma unroll
                for (int mi = 0; mi < 4; mi++)
                    #pragma unroll
                    for (int reg = 0; reg < 4; reg++) {
                        const int l = mi * 16 + quad * 4 + reg;
                        const int cw = (l >> 1) ^ g4;
                        T[dl * 64 + cw * 2 + (l & 1)] = f2bf(acc[mi][ni][reg]);
                    }
            }
            #pragma unroll
            for (int s = 0; s < 4; s++) {
                const int dl = s * 8 + (lane >> 3);
                const int d  = p * 32 + dl;
                const int g4 = (dl & 7) << 2;
                const int pd = ((lane & 7) * 4) ^ g4;
                uint4 val = *(const uint4*)&T[dl * 64 + pd * 2];
                *(uint4*)&vT[((size_t)(b * NH + h) * HD + d) * LL + lg] = val;
            }
        }
    } else {
        unsigned short* dst = (which == 0) ? qws : kws;
        #pragma unroll
        for (int mi = 0; mi < 4; mi++) {
            #pragma unroll
            for (int reg = 0; reg < 4; reg++) {
                const int row = m0 + wm * 64 + mi * 16 + quad * 4 + reg;
                const int b = row >> 11, l = row & (LL - 1);
                #pragma unroll
                for (int ni = 0; ni < 4; ni++) {
                    const int d = ni * 16 + lr;
                    const float c = cosb[l * HD + d];
                    const float s = sinb[l * HD + d];
                    const float partner = (d < 32) ? -acc[mi][ni + 2][reg]
                                                   :  acc[mi][ni - 2][reg];
                    dst[((size_t)(b * NH + h) * LL + l) * HD + d] =
                        f2bf(acc[mi][ni][reg] * c + partner * s);
                }
            }
        }
    }
}

// ---------------------------------------------------------------------------
// Kernel 2: sliding-window attention — in-register P + software-pipelined
// loads (this round). Round-8 passed but was perf-neutral; PMC shows all
// pipes >=85% idle -> unhidden load latency. Two exposures fixed:
//  (a) all 4 K ds_read_b128s issue at kc top (sub1's ~120cyc LDS latency
//      hides under sub0's MFMA+exp; zero extra VGPR),
//  (b) V loads for kc+1 issue cross-iteration (bvn double-buffer, +16 VGPR,
//      ~500cyc global latency covered by a full kc body).
// Everything else identical to the round-8 version that passed.
// ---------------------------------------------------------------------------
#define SW_SPAN 384
__global__ __launch_bounds__(512, 4) void swa_attn(
    const unsigned short* __restrict__ qws,
    const unsigned short* __restrict__ kws,
    const unsigned short* __restrict__ vT,
    unsigned short* __restrict__ aout)
{
    __shared__ __align__(16) unsigned short Ks[SW_SPAN * 64];     // 48 KB

    const int t = threadIdx.x;
    const int lane = t & 63, w = t >> 6;          // w = 0..7

    const int id   = (blockIdx.z * NH + blockIdx.y) * 16 + blockIdx.x; // 0..511
    const int xcd  = id & 7, slot = id >> 3;      // slot 0..63
    const int hb   = xcd * 4 + (slot >> 4);       // 0..31
    const int qb   = slot & 15;
    const int h = hb & 15, b = hb >> 4;

    const int q0 = qb * 128;                      // block's 128-query tile
    const int base_key = q0 - WIN;

    const int lr = lane & 15, quad = lane >> 4, ko = quad * 8;
    const size_t base = ((size_t)(b * NH + h)) * LL * HD;
    const unsigned short* Q  = qws + base;
    const unsigned short* K  = kws + base;
    const unsigned short* VT = vT + base;         // [64][LL]

    {   // stage 384 K rows: 6 passes x 64 rows (512 thr x 16B = 8KB/pass)
        const int rsub = t >> 3;                  // 0..63
        const int csw  = (t & 7) ^ (rsub & 7);
        #pragma unroll
        for (int p = 0; p < 6; p++) {
            const int j = min(max(base_key + p * 64 + rsub, 0), LL - 1);
            gll16(K + (size_t)j * HD + csw * 8, &Ks[p * 4096 + t * 8]);
        }
    }
    const int i0 = q0 + w * 16;               // wave's query tile
    const int wkey = i0 - WIN;                // wave's key-span start
    const bf16x8 qa0 = load8bf(Q + (size_t)(i0 + lr) * HD + ko);
    const bf16x8 qa1 = load8bf(Q + (size_t)(i0 + lr) * HD + 32 + ko);
    __syncthreads();                          // the only barrier

    float rowsumL = 0.f;
    f32x4 o[4];
    #pragma unroll
    for (int nt = 0; nt < 4; nt++) o[nt] = 0.0f;

    // shuffle source lanes: group {lr, lr+16, lr+32, lr+48}
    const int srcA = (quad & 1) * 32 + lr;
    const int srcB = srcA + 16;
    const bool useB = (quad >= 2);

    if (q0 >= WIN) {
        // ================= fast path: wkey >= 0 =================
        bf16x8 bv[4];
        {   // V chunk 0 (wkey >= 0, no clamp needed at kc=0)
            const int kb = wkey + ko;
            #pragma unroll
            for (int nt = 0; nt < 4; nt++)
                bv[nt] = load8bf(VT + (size_t)(nt * 16 + lr) * LL + kb);
        }
        #pragma unroll
        for (int kc = 0; kc < 9; kc++) {
            const int kt0 = 2 * kc, kt1 = 2 * kc + 1;
            // ---- (a) all K fragment reads for this kc, issued together ----
            const int R0 = w * 16 + kt0 * 16 + lr;
            const bf16x8 kf0a = load8bf(&Ks[R0 * 64 + ((quad       ^ (R0 & 7)) * 8)]);
            const bf16x8 kf0b = load8bf(&Ks[R0 * 64 + (((quad + 4) ^ (R0 & 7)) * 8)]);
            bf16x8 kf1a, kf1b;
            if (kt1 <= 16) {
                const int R1 = w * 16 + kt1 * 16 + lr;
                kf1a = load8bf(&Ks[R1 * 64 + ((quad       ^ (R1 & 7)) * 8)]);
                kf1b = load8bf(&Ks[R1 * 64 + (((quad + 4) ^ (R1 & 7)) * 8)]);
            }
            // ---- (b) prefetch V for kc+1 (consumed next iteration) ----
            bf16x8 bvn[4];
            if (kc < 8) {
                int kb = wkey + (kc + 1) * 32 + ko;
                kb = min(kb, LL - 8);            // tail clamp: P==0 there
                #pragma unroll
                for (int nt = 0; nt < 4; nt++)
                    bvn[nt] = load8bf(VT + (size_t)(nt * 16 + lr) * LL + kb);
            }
            unsigned L0, H0, L1, H1;
            // ---- sub 0: kt even; masks at kt==0 and kt==16 ----
            {
                f32x4 s = 0.0f;
                __builtin_amdgcn_s_setprio(1);
                s = __builtin_amdgcn_mfma_f32_16x16x32_bf16(kf0a, qa0, s, 0, 0, 0);
                s = __builtin_amdgcn_mfma_f32_16x16x32_bf16(kf0b, qa1, s, 0, 0, 0);
                __builtin_amdgcn_s_setprio(0);
                float e[4];
                #pragma unroll
                for (int reg = 0; reg < 4; reg++) {
                    const int qk = quad * 4 + reg;       // key index in tile
                    float ee = __expf(s[reg] * 0.125f);
                    if (kt0 == 0)  ee = (qk >= lr) ? ee : 0.0f;
                    if (kt0 == 16) ee = (qk <= lr) ? ee : 0.0f;
                    rowsumL += ee;
                    e[reg] = ee;
                }
                L0 = pack2bf(e[0], e[1]); H0 = pack2bf(e[2], e[3]);
            }
            // ---- sub 1: kt odd; never edge-masked; 17 = pad ----
            if (kt1 > 16) {
                L1 = 0u; H1 = 0u;
            } else {
                f32x4 s = 0.0f;
                __builtin_amdgcn_s_setprio(1);
                s = __builtin_amdgcn_mfma_f32_16x16x32_bf16(kf1a, qa0, s, 0, 0, 0);
                s = __builtin_amdgcn_mfma_f32_16x16x32_bf16(kf1b, qa1, s, 0, 0, 0);
                __builtin_amdgcn_s_setprio(0);
                float e[4];
                #pragma unroll
                for (int reg = 0; reg < 4; reg++) {
                    const float ee = __expf(s[reg] * 0.125f);
                    rowsumL += ee;
                    e[reg] = ee;
                }
                L1 = pack2bf(e[0], e[1]); H1 = pack2bf(e[2], e[3]);
            }
            // ---- in-register P redistribution (8 shfl + 4 select) ----
            {
                const int a0 = __shfl((int)L0, srcA);
                const int a1 = __shfl((int)H0, srcA);
                const int a2 = __shfl((int)L0, srcB);
                const int a3 = __shfl((int)H0, srcB);
                const int b0 = __shfl((int)L1, srcA);
                const int b1 = __shfl((int)H1, srcA);
                const int b2 = __shfl((int)L1, srcB);
                const int b3 = __shfl((int)H1, srcB);
                uint4 w4;
                w4.x = (unsigned)(useB ? b0 : a0);
                w4.y = (unsigned)(useB ? b1 : a1);
                w4.z = (unsigned)(useB ? b2 : a2);
                w4.w = (unsigned)(useB ? b3 : a3);
                const bf16x8 pa = __builtin_bit_cast(bf16x8, w4);
                __builtin_amdgcn_s_setprio(1);
                #pragma unroll
                for (int nt = 0; nt < 4; nt++)
                    o[nt] = __builtin_amdgcn_mfma_f32_16x16x32_bf16(pa, bv[nt], o[nt], 0, 0, 0);
                __builtin_amdgcn_s_setprio(0);
            }
            if (kc < 8) {
                #pragma unroll
                for (int nt = 0; nt < 4; nt++) bv[nt] = bvn[nt];
            }
        }
    } else {
        // ================= slow path (q0 < WIN): full masks =================
        #pragma unroll
        for (int kc = 0; kc < 9; kc++) {
            bf16x8 bv[4];
            {
                int kb = wkey + kc * 32 + ko;
                kb = min(max(kb, 0), LL - 8);
                #pragma unroll
                for (int nt = 0; nt < 4; nt++)
                    bv[nt] = load8bf(VT + (size_t)(nt * 16 + lr) * LL + kb);
            }
            unsigned LH[2][2];
            #pragma unroll
            for (int sub = 0; sub < 2; sub++) {
                const int kt = 2 * kc + sub;
                const int R = min(w * 16 + kt * 16 + lr, SW_SPAN - 1);
                const bf16x8 kb0 = load8bf(&Ks[R * 64 + ((quad       ^ (R & 7)) * 8)]);
                const bf16x8 kb1 = load8bf(&Ks[R * 64 + (((quad + 4) ^ (R & 7)) * 8)]);
                f32x4 s = 0.0f;
                s = __builtin_amdgcn_mfma_f32_16x16x32_bf16(kb0, qa0, s, 0, 0, 0);
                s = __builtin_amdgcn_mfma_f32_16x16x32_bf16(kb1, qa1, s, 0, 0, 0);
                float e[4];
                #pragma unroll
                for (int reg = 0; reg < 4; reg++) {
                    const int qk = quad * 4 + reg;
                    const int i = i0 + lr;                    // query row
                    const int j = wkey + kt * 16 + qk;        // key index
                    const bool valid = (j >= 0) && (j <= i) && (j >= i - WIN);
                    const float ee = valid ? __expf(s[reg] * 0.125f) : 0.0f;
                    rowsumL += ee;
                    e[reg] = ee;
                }
                LH[sub][0] = pack2bf(e[0], e[1]); LH[sub][1] = pack2bf(e[2], e[3]);
            }
            {
                const int a0 = __shfl((int)LH[0][0], srcA);
                const int a1 = __shfl((int)LH[0][1], srcA);
                const int a2 = __shfl((int)LH[0][0], srcB);
                const int a3 = __shfl((int)LH[0][1], srcB);
                const int b0 = __shfl((int)LH[1][0], srcA);
                const int b1 = __shfl((int)LH[1][1], srcA);
                const int b2 = __shfl((int)LH[1][0], srcB);
                const int b3 = __shfl((int)LH[1][1], srcB);
                uint4 w4;
                w4.x = (unsigned)(useB ? b0 : a0);
                w4.y = (unsigned)(useB ? b1 : a1);
                w4.z = (unsigned)(useB ? b2 : a2);
                w4.w = (unsigned)(useB ? b3 : a3);
                const bf16x8 pa = __builtin_bit_cast(bf16x8, w4);
                #pragma unroll
                for (int nt = 0; nt < 4; nt++)
                    o[nt] = __builtin_amdgcn_mfma_f32_16x16x32_bf16(pa, bv[nt], o[nt], 0, 0, 0);
            }
        }
    }

    // rowsum: butterfly over the 4 quads -> every lane has full sum for q=lr
    rowsumL += __shfl_xor(rowsumL, 16);
    rowsumL += __shfl_xor(rowsumL, 32);
    const float inv = 1.0f / rowsumL;

    // o[nt][reg] is for q-row quad*4+reg -> fetch that row's inv
    float invq[4];
    #pragma unroll
    for (int reg = 0; reg < 4; reg++)
        invq[reg] = __shfl(inv, quad * 4 + reg);

    #pragma unroll
    for (int nt = 0; nt < 4; nt++) {
        #pragma unroll
        for (int reg = 0; reg < 4; reg++) {
            const int i = i0 + quad * 4 + reg;
            const int d = nt * 16 + lr;
            aout[((size_t)(b * LL + i)) * DIM + h * HD + d] =
                f2bf(o[nt][reg] * invq[reg]);
        }
    }
}

// ---------------------------------------------------------------------------
// Kernel 3: output projection. 64x64 tiles -> 1024 blocks (4/CU), BK=64,
// swizzled staging, XCD-aware remap. Wave = 32M x 32N.
// ---------------------------------------------------------------------------
__global__ __launch_bounds__(256, 4) void out_gemm(
    const unsigned short* __restrict__ A,
    const unsigned short* __restrict__ Wob,
    float* __restrict__ out)
{
    __shared__ __align__(16) unsigned short smem[64 * 64 + 64 * 64];  // 16 KB
    unsigned short* As = smem;
    unsigned short* Bs = smem + 64 * 64;
    const int t = threadIdx.x;
    const int lane = t & 63, w = t >> 6;
    const int wm = w >> 1, wn = w & 1;
    const int lr = lane & 15, quad = lane >> 4;

    const int id   = blockIdx.y * 16 + blockIdx.x;   // 0..1023
    const int xcd  = id & 7, slot = id >> 3;         // 128 slots per XCD
    const int bx   = (xcd & 1) * 8 + (slot & 7);
    const int by   = (xcd >> 1) * 16 + (slot >> 3);
    const int n0 = bx * 64, m0 = by * 64;

    f32x4 acc[2][2];
    for (int i = 0; i < 2; i++) for (int j = 0; j < 2; j++) acc[i][j] = 0.0f;

    const int rsub = t >> 3;
    const int csw  = (t & 7) ^ (rsub & 7);
    const int sw7  = lr & 7;

    for (int k0 = 0; k0 < DIM; k0 += 64) {
        __syncthreads();
        #pragma unroll
        for (int p = 0; p < 2; p++) {
            const int row = p * 32 + rsub;
            gll16(A   + (size_t)(m0 + row) * DIM + k0 + csw * 8,
                  &As[p * 2048 + t * 8]);
            gll16(Wob + (size_t)(n0 + row) * DIM + k0 + csw * 8,
                  &Bs[p * 2048 + t * 8]);
        }
        __syncthreads();
        #pragma unroll
        for (int kk = 0; kk < 2; kk++) {
            bf16x8 af[2], bfr[2];
            #pragma unroll
            for (int mi = 0; mi < 2; mi++) {
                const int R = wm * 32 + mi * 16 + lr;
                af[mi] = load8bf(&As[R * 64 + (((kk * 4 + quad) ^ sw7) * 8)]);
            }
            #pragma unroll
            for (int ni = 0; ni < 2; ni++) {
                const int R = wn * 32 + ni * 16 + lr;
                bfr[ni] = load8bf(&Bs[R * 64 + (((kk * 4 + quad) ^ sw7) * 8)]);
            }
            #pragma unroll
            for (int mi = 0; mi < 2; mi++)
                #pragma unroll
                for (int ni = 0; ni < 2; ni++)
                    acc[mi][ni] = __builtin_amdgcn_mfma_f32_16x16x32_bf16(
                        af[mi], bfr[ni], acc[mi][ni], 0, 0, 0);
        }
    }

    #pragma unroll
    for (int mi = 0; mi < 2; mi++) {
        #pragma unroll
        for (int reg = 0; reg < 4; reg++) {
            const int row = m0 + wm * 32 + mi * 16 + quad * 4 + reg;
            #pragma unroll
            for (int ni = 0; ni < 2; ni++) {
                const int col = n0 + wn * 32 + ni * 16 + lr;
                out[(size_t)row * DIM + col] = acc[mi][ni][reg];
            }
        }
    }
}

extern "C" void kernel_launch(void* const* d_in, const int* in_sizes, int n_in,
                              void* d_out, int out_size, void* d_ws, size_t ws_size,
                              hipStream_t stream)
{
    const float* x    = (const float*)d_in[0];
    const float* cosb = (const float*)d_in[1];
    const float* sinb = (const float*)d_in[2];
    const float* Wq   = (const float*)d_in[3];
    const float* Wk   = (const float*)d_in[4];
    const float* Wv   = (const float*)d_in[5];
    const float* Wo   = (const float*)d_in[6];
    float* out = (float*)d_out;

    unsigned short* xb   = (unsigned short*)d_ws;
    unsigned short* wqkv = xb + (size_t)MM * DIM;
    unsigned short* wob  = wqkv + (size_t)NQKV * DIM;
    unsigned short* qws  = wob + (size_t)DIM * DIM;
    unsigned short* kws  = qws + (size_t)BB * NH * LL * HD;
    unsigned short* vT   = kws + (size_t)BB * NH * LL * HD;
    unsigned short* aws  = xb;   // alias: xb dead after qkv_gemm

    convert_inputs<<<dim3(SEG / (256 * 8), 8), 256, 0, stream>>>(
        x, Wq, Wk, Wv, Wo, xb, wqkv, wob);
    qkv_gemm<<<dim3(NQKV / 128, MM / 128), 256, 0, stream>>>(
        xb, wqkv, cosb, sinb, qws, kws, vT);
    swa_attn<<<dim3(LL / 128, NH, BB), 512, 0, stream>>>(qws, kws, vT, aws);
    out_gemm<<<dim3(DIM / 64, MM / 64), 256, 0, stream>>>(aws, wob, out);
}